// Round 4
// baseline (608.379 us; speedup 1.0000x reference)
//
#include <hip/hip_runtime.h>
#include <hip/hip_bf16.h>
#include <math.h>

#define D_MODEL 1024
#define DD (1024 * 1024)

typedef unsigned short ushort_t;
using short8 = __attribute__((ext_vector_type(8))) short;   // 8 bf16 (4 VGPRs)
using f32x4  = __attribute__((ext_vector_type(4))) float;   // 4 fp32 acc

#define ACT_NONE 0
#define ACT_SILU 1

__device__ __forceinline__ float bf2f(ushort_t u) {
    return __uint_as_float(((unsigned int)u) << 16);
}
__device__ __forceinline__ ushort_t f2bf(float f) {
    unsigned int x = __float_as_uint(f);
    x += 0x7fffu + ((x >> 16) & 1u);   // round-to-nearest-even
    return (ushort_t)(x >> 16);
}

#define GL2LDS(gp, lp)                                                         \
    __builtin_amdgcn_global_load_lds(                                          \
        (const __attribute__((address_space(1))) void*)(gp),                   \
        (__attribute__((address_space(3))) void*)(lp), 16, 0, 0)

// ---------------------------------------------------------------------------
// bf16 GEMM, restructured K-loop:
//  - A staged via global_load_lds into double-buffered LDS (8KB x2),
//    staging for tile it+1 issued AFTER the barrier -> overlaps MFMA of tile it.
//  - B (weights, L2-resident) loaded straight to registers as 16B fragments,
//    prefetched one iteration ahead. No B in LDS: halves LDS traffic.
//  - ONE barrier per K-iter.
// A: M x 1024 bf16 row-major.  Bt: 1024 x 1024 bf16, N-major (Bt[n][k]).
// C: bf16 (OUTF32=0) or fp32 (OUTF32=1), M x 1024 row-major.
// ---------------------------------------------------------------------------
template <int ACT, int OUTF32, int BIASF>
__global__ __launch_bounds__(256) void gemm_bf16(
    const ushort_t* __restrict__ A,
    const ushort_t* __restrict__ Bt,
    const float* __restrict__ bias,
    void* __restrict__ Cv, int M)
{
    constexpr int K = 1024, N = 1024, NIT = K / 32;
    __shared__ ushort_t As[2][128 * 32];

    const int tid  = threadIdx.x;
    const int lane = tid & 63;
    const int wave = tid >> 6;
    const int quad = lane >> 4;
    const int lr   = lane & 15;
    const int bm   = blockIdx.x;
    const int bn   = blockIdx.y;
    const int wm   = (wave >> 1) * 64;
    const int wn   = (wave & 1) * 64;

    f32x4 acc[4][4];
#pragma unroll
    for (int i = 0; i < 4; i++)
#pragma unroll
        for (int j = 0; j < 4; j++) acc[i][j] = (f32x4){0.f, 0.f, 0.f, 0.f};

    // A staging coords: 512 16B-chunks (128 rows x 4 k-chunks), 2 per thread,
    // k-chunk XOR-swizzled so fragment ds_read_b128 is bank-conflict-free.
    const int ci0 = tid, ci1 = tid + 256;
    const int am0 = ci0 >> 2, akc0 = (ci0 & 3) ^ ((am0 >> 1) & 3);
    const int am1 = ci1 >> 2, akc1 = (ci1 & 3) ^ ((am1 >> 1) & 3);
    const ushort_t* Ab = A + (size_t)(bm * 128) * K;
    const ushort_t* g0 = Ab + (size_t)am0 * K + akc0 * 8;
    const ushort_t* g1 = Ab + (size_t)am1 * K + akc1 * 8;

    // prologue: stage tile 0 into As[0]; prefetch B frags for k0=0
    GL2LDS(g0, &As[0][ci0 * 8]);
    GL2LDS(g1, &As[0][ci1 * 8]);

    const ushort_t* Bp = Bt + (size_t)(bn * 128 + wn + lr) * K + quad * 8;
    short8 bnxt[4];
#pragma unroll
    for (int t = 0; t < 4; t++)
        bnxt[t] = *(const short8*)(Bp + (size_t)t * 16 * K);

    for (int it = 0; it < NIT; ++it) {
        __syncthreads();   // drains staging of tile it (issued one iter ago)
        const int cur = it & 1;
        if (it + 1 < NIT) {
            const int k0n = (it + 1) * 32;
            GL2LDS(g0 + k0n, &As[cur ^ 1][ci0 * 8]);
            GL2LDS(g1 + k0n, &As[cur ^ 1][ci1 * 8]);
        }
        short8 bcur[4];
#pragma unroll
        for (int t = 0; t < 4; t++) bcur[t] = bnxt[t];
        if (it + 1 < NIT) {
            const int k0n = (it + 1) * 32;
#pragma unroll
            for (int t = 0; t < 4; t++)
                bnxt[t] = *(const short8*)(Bp + (size_t)t * 16 * K + k0n);
        }
        short8 af[4];
#pragma unroll
        for (int t = 0; t < 4; t++) {
            const int m = wm + t * 16 + lr;
            af[t] = *(const short8*)(&As[cur][m * 32 + ((quad ^ ((m >> 1) & 3)) * 8)]);
        }
#pragma unroll
        for (int mt = 0; mt < 4; mt++)
#pragma unroll
            for (int nt = 0; nt < 4; nt++)
                acc[mt][nt] = __builtin_amdgcn_mfma_f32_16x16x32_bf16(
                    af[mt], bcur[nt], acc[mt][nt], 0, 0, 0);
    }

    // ---- epilogue: bias (+SiLU), direct scalar stores (R2 style) ----
    float bv[4];
#pragma unroll
    for (int nt = 0; nt < 4; nt++)
        bv[nt] = BIASF ? bias[bn * 128 + wn + nt * 16 + lr] : 0.f;

#pragma unroll
    for (int mt = 0; mt < 4; mt++) {
#pragma unroll
        for (int nt = 0; nt < 4; nt++) {
            const int col = bn * 128 + wn + nt * 16 + lr;
#pragma unroll
            for (int r = 0; r < 4; r++) {
                const int row = bm * 128 + wm + mt * 16 + quad * 4 + r;
                float v = acc[mt][nt][r] + bv[nt];
                if (ACT == ACT_SILU) v = v / (1.f + __expf(-v));
                if (OUTF32)
                    ((float*)Cv)[(size_t)row * N + col] = v;
                else
                    ((ushort_t*)Cv)[(size_t)row * N + col] = f2bf(v);
            }
        }
    }
}

// ---------------------------------------------------------------------------
// In-place LayerNorm over bf16 rows of 1024, fp32 math, eps=1e-5.
// ---------------------------------------------------------------------------
__global__ __launch_bounds__(256) void layernorm_bf16(ushort_t* __restrict__ X)
{
    const int row = blockIdx.x;
    const int tid = threadIdx.x;
    ushort_t* x = X + (size_t)row * D_MODEL + tid * 4;

    uint2 u = *(uint2*)x;
    float a = bf2f(u.x & 0xffff), b = bf2f(u.x >> 16);
    float c = bf2f(u.y & 0xffff), d = bf2f(u.y >> 16);
    float s = a + b + c + d;
    float ss = a * a + b * b + c * c + d * d;

#pragma unroll
    for (int off = 32; off > 0; off >>= 1) {
        s += __shfl_down(s, off);
        ss += __shfl_down(ss, off);
    }
    __shared__ float sbuf[4], ssbuf[4];
    const int wave = tid >> 6;
    if ((tid & 63) == 0) { sbuf[wave] = s; ssbuf[wave] = ss; }
    __syncthreads();
    const float S = sbuf[0] + sbuf[1] + sbuf[2] + sbuf[3];
    const float SS = ssbuf[0] + ssbuf[1] + ssbuf[2] + ssbuf[3];
    const float mu = S * (1.f / D_MODEL);
    const float var = SS * (1.f / D_MODEL) - mu * mu;
    const float r = rsqrtf(var + 1e-5f);

    a = (a - mu) * r; b = (b - mu) * r; c = (c - mu) * r; d = (d - mu) * r;
    u.x = (unsigned)f2bf(a) | ((unsigned)f2bf(b) << 16);
    u.y = (unsigned)f2bf(c) | ((unsigned)f2bf(d) << 16);
    *(uint2*)x = u;
}

// ---------------------------------------------------------------------------
// fp32 -> bf16 bulk convert (8 elems/thread).
// ---------------------------------------------------------------------------
__global__ __launch_bounds__(256) void f32_to_bf16(
    const float* __restrict__ in, ushort_t* __restrict__ out, int n8)
{
    int i = blockIdx.x * 256 + threadIdx.x;
    if (i >= n8) return;
    const float4* p = (const float4*)(in + (size_t)i * 8);
    float4 v0 = p[0], v1 = p[1];
    union { ushort_t u[8]; uint4 v; } pk;
    pk.u[0] = f2bf(v0.x); pk.u[1] = f2bf(v0.y);
    pk.u[2] = f2bf(v0.z); pk.u[3] = f2bf(v0.w);
    pk.u[4] = f2bf(v1.x); pk.u[5] = f2bf(v1.y);
    pk.u[6] = f2bf(v1.z); pk.u[7] = f2bf(v1.w);
    *(uint4*)(out + (size_t)i * 8) = pk.v;
}

// ---------------------------------------------------------------------------
// Weight prep, one dispatch. z=0..4: transpose+convert (wq, mlp0..2, w_out)
// fp32 K-major -> bf16 N-major at out+z*DD.  z=5: plain convert of W3
// (mlp_w[3]) -> out+5*DD.
// ---------------------------------------------------------------------------
__global__ __launch_bounds__(256) void prep_weights(
    const float* __restrict__ wq, const float* __restrict__ mlp_w,
    const float* __restrict__ w_out, ushort_t* __restrict__ out)
{
    const int z = blockIdx.z;
    const int r = threadIdx.x >> 5;    // 0..7
    const int c = threadIdx.x & 31;    // 0..31
    const int k0 = blockIdx.x * 32;
    const int n0 = blockIdx.y * 32;

    if (z == 5) {   // plain convert W3
        const float* src = mlp_w + (size_t)3 * DD;
        ushort_t* dst = out + (size_t)5 * DD;
#pragma unroll
        for (int i = 0; i < 4; i++) {
            size_t idx = (size_t)(k0 + r + 8 * i) * D_MODEL + n0 + c;
            dst[idx] = f2bf(src[idx]);
        }
        return;
    }
    const float* src = (z == 0) ? wq : (z < 4) ? (mlp_w + (size_t)(z - 1) * DD) : w_out;
    ushort_t* dst = out + (size_t)z * DD;

    __shared__ float tile[32][33];
#pragma unroll
    for (int i = 0; i < 4; i++)
        tile[r + 8 * i][c] = src[(size_t)(k0 + r + 8 * i) * D_MODEL + n0 + c];
    __syncthreads();
#pragma unroll
    for (int i = 0; i < 4; i++)
        dst[(size_t)(n0 + r + 8 * i) * D_MODEL + k0 + c] = f2bf(tile[c][r + 8 * i]);
}

// ---------------------------------------------------------------------------
// bf[n] = sum_k b3[k] * Wout[k][n] + bout[n]   (fp32)
// ---------------------------------------------------------------------------
__global__ __launch_bounds__(256) void bias_compose(
    const float* __restrict__ b3, const float* __restrict__ w_out,
    const float* __restrict__ bout, float* __restrict__ bf)
{
    int n = blockIdx.x * 256 + threadIdx.x;
    float s = 0.f;
    for (int k = 0; k < D_MODEL; k++)
        s = fmaf(b3[k], w_out[(size_t)k * D_MODEL + n], s);
    bf[n] = s + bout[n];
}

// ---------------------------------------------------------------------------
extern "C" void kernel_launch(void* const* d_in, const int* in_sizes, int n_in,
                              void* d_out, int out_size, void* d_ws, size_t ws_size,
                              hipStream_t stream)
{
    const float* x     = (const float*)d_in[0];
    const float* wq    = (const float*)d_in[1];
    const float* bq    = (const float*)d_in[2];
    const float* mlp_w = (const float*)d_in[3];
    const float* mlp_b = (const float*)d_in[4];
    const float* w_out = (const float*)d_in[5];
    const float* b_out = (const float*)d_in[6];

    const int D = D_MODEL;
    const int M = in_sizes[0] / D;   // 16384

    // ws layout (ushort units):
    // wt[0..5)=transposed weights | [5DD,6DD)=W3 plain bf16 | [6DD,7DD)=WfT
    // | Q (M*D) | bf (1024 fp32)
    ushort_t* wt  = (ushort_t*)d_ws;
    ushort_t* w3b = wt + (size_t)5 * DD;
    ushort_t* wtF = wt + (size_t)6 * DD;
    ushort_t* Q   = wt + (size_t)7 * DD;
    float*    bf  = (float*)(Q + (size_t)M * D);
    ushort_t* P   = (ushort_t*)d_out;   // bf16 acts alias d_out's 64MB fp32

    // 1. weight prep (transposes + W3 convert), one dispatch
    prep_weights<<<dim3(32, 32, 6), 256, 0, stream>>>(wq, mlp_w, w_out, wt);
    // 2. bf = b3 @ Wout + bout
    bias_compose<<<4, 256, 0, stream>>>(mlp_b + 3 * D, w_out, b_out, bf);
    // 3. Wf^T = Wout^T @ W3^T  (N-major rep of Wf = W3*Wout)
    gemm_bf16<ACT_NONE, 0, 0><<<dim3(8, 8), 256, 0, stream>>>(wt + (size_t)4 * DD, w3b, nullptr, wtF, 1024);
    // 4. x -> bf16 into Q
    f32_to_bf16<<<(M * D / 8 + 255) / 256, 256, 0, stream>>>(x, Q, M * D / 8);

    dim3 grid(M / 128, D / 128);
    // 5. q = x @ wq + bq -> P
    gemm_bf16<ACT_NONE, 0, 1><<<grid, 256, 0, stream>>>(Q, wt + (size_t)0 * DD, bq, P, M);
    // 6. LN in place on P
    layernorm_bf16<<<M, 256, 0, stream>>>(P);
    // 7-9. MLP layers 0..2 with SiLU
    gemm_bf16<ACT_SILU, 0, 1><<<grid, 256, 0, stream>>>(P, wt + (size_t)1 * DD, mlp_b + 0 * D, Q, M);
    gemm_bf16<ACT_SILU, 0, 1><<<grid, 256, 0, stream>>>(Q, wt + (size_t)2 * DD, mlp_b + 1 * D, P, M);
    gemm_bf16<ACT_SILU, 0, 1><<<grid, 256, 0, stream>>>(P, wt + (size_t)3 * DD, mlp_b + 2 * D, Q, M);
    // 10. fused (layer3 + out proj): out = h3 @ Wf + bf -> d_out fp32
    //     (reads Q in ws, so no alias hazard with d_out)
    gemm_bf16<ACT_NONE, 1, 1><<<grid, 256, 0, stream>>>(Q, wtF, bf, d_out, M);
}

// Round 5
// 421.718 us; speedup vs baseline: 1.4426x; 1.4426x over previous
//
#include <hip/hip_runtime.h>
#include <hip/hip_bf16.h>
#include <math.h>

#define D_MODEL 1024
#define DD (1024 * 1024)

typedef unsigned short ushort_t;
using short8 = __attribute__((ext_vector_type(8))) short;   // 8 bf16 (4 VGPRs)
using f32x4  = __attribute__((ext_vector_type(4))) float;   // 4 fp32 acc

#define ACT_NONE 0
#define ACT_SILU 1

__device__ __forceinline__ float bf2f(ushort_t u) {
    return __uint_as_float(((unsigned int)u) << 16);
}
__device__ __forceinline__ ushort_t f2bf(float f) {
    unsigned int x = __float_as_uint(f);
    x += 0x7fffu + ((x >> 16) & 1u);   // round-to-nearest-even
    return (ushort_t)(x >> 16);
}

#define GL2LDS(gp, lp)                                                         \
    __builtin_amdgcn_global_load_lds(                                          \
        (const __attribute__((address_space(1))) void*)(gp),                   \
        (__attribute__((address_space(3))) void*)(lp), 16, 0, 0)

// ---------------------------------------------------------------------------
// bf16 GEMM — exact R2 structure (measured 57.7us/GEMM, MfmaUtil 24%):
// 128x128 tile, BK=32, 16x16x32 MFMA, 4 waves x (4x4) frags,
// A and B both staged via global_load_lds (16B), XOR k-chunk swizzle,
// 2 barriers per K-iter, direct scalar-store epilogue.
// A: M x 1024 bf16 row-major.  Bt: 1024 x 1024 bf16, N-major (Bt[n][k]).
// ---------------------------------------------------------------------------
template <int ACT, int OUTF32, int BIASF>
__global__ __launch_bounds__(256) void gemm_bf16(
    const ushort_t* __restrict__ A,
    const ushort_t* __restrict__ Bt,
    const float* __restrict__ bias,
    void* __restrict__ Cv, int M)
{
    constexpr int K = 1024, N = 1024;
    __shared__ ushort_t As[128 * 32];
    __shared__ ushort_t Bs[128 * 32];

    const int tid  = threadIdx.x;
    const int lane = tid & 63;
    const int wave = tid >> 6;
    const int quad = lane >> 4;
    const int lr   = lane & 15;
    const int bm   = blockIdx.x;
    const int bn   = blockIdx.y;
    const int wm   = (wave >> 1) * 64;
    const int wn   = (wave & 1) * 64;

    f32x4 acc[4][4];
#pragma unroll
    for (int i = 0; i < 4; i++)
#pragma unroll
        for (int j = 0; j < 4; j++) acc[i][j] = (f32x4){0.f, 0.f, 0.f, 0.f};

    int ci0 = tid, ci1 = tid + 256;
    int am0 = ci0 >> 2, akc0 = (ci0 & 3) ^ ((am0 >> 1) & 3);
    int am1 = ci1 >> 2, akc1 = (ci1 & 3) ^ ((am1 >> 1) & 3);
    const ushort_t* Ab = A + (size_t)(bm * 128) * K;
    const ushort_t* Bb = Bt + (size_t)(bn * 128) * K;

    for (int k0 = 0; k0 < K; k0 += 32) {
        GL2LDS(Ab + (size_t)am0 * K + k0 + akc0 * 8, As + ci0 * 8);
        GL2LDS(Ab + (size_t)am1 * K + k0 + akc1 * 8, As + ci1 * 8);
        GL2LDS(Bb + (size_t)am0 * K + k0 + akc0 * 8, Bs + ci0 * 8);
        GL2LDS(Bb + (size_t)am1 * K + k0 + akc1 * 8, Bs + ci1 * 8);
        __syncthreads();

        short8 af[4], bfr[4];
#pragma unroll
        for (int t = 0; t < 4; t++) {
            int m = wm + t * 16 + lr;
            af[t] = *(const short8*)(As + m * 32 + ((quad ^ ((m >> 1) & 3)) * 8));
            int n = wn + t * 16 + lr;
            bfr[t] = *(const short8*)(Bs + n * 32 + ((quad ^ ((n >> 1) & 3)) * 8));
        }
#pragma unroll
        for (int mt = 0; mt < 4; mt++)
#pragma unroll
            for (int nt = 0; nt < 4; nt++)
                acc[mt][nt] = __builtin_amdgcn_mfma_f32_16x16x32_bf16(
                    af[mt], bfr[nt], acc[mt][nt], 0, 0, 0);
        __syncthreads();
    }

    // epilogue: bias (+SiLU), direct stores (R2 style — store pipe not the wall)
    float bv[4];
#pragma unroll
    for (int nt = 0; nt < 4; nt++)
        bv[nt] = BIASF ? bias[bn * 128 + wn + nt * 16 + lr] : 0.f;

#pragma unroll
    for (int mt = 0; mt < 4; mt++) {
#pragma unroll
        for (int nt = 0; nt < 4; nt++) {
            const int col = bn * 128 + wn + nt * 16 + lr;
#pragma unroll
            for (int r = 0; r < 4; r++) {
                const int row = bm * 128 + wm + mt * 16 + quad * 4 + r;
                float v = acc[mt][nt][r] + bv[nt];
                if (ACT == ACT_SILU) v = v / (1.f + __expf(-v));
                if (OUTF32)
                    ((float*)Cv)[(size_t)row * N + col] = v;
                else
                    ((ushort_t*)Cv)[(size_t)row * N + col] = f2bf(v);
            }
        }
    }
}

// ---------------------------------------------------------------------------
// In-place LayerNorm over bf16 rows of 1024, fp32 math, eps=1e-5.
// ---------------------------------------------------------------------------
__global__ __launch_bounds__(256) void layernorm_bf16(ushort_t* __restrict__ X)
{
    const int row = blockIdx.x;
    const int tid = threadIdx.x;
    ushort_t* x = X + (size_t)row * D_MODEL + tid * 4;

    uint2 u = *(uint2*)x;
    float a = bf2f(u.x & 0xffff), b = bf2f(u.x >> 16);
    float c = bf2f(u.y & 0xffff), d = bf2f(u.y >> 16);
    float s = a + b + c + d;
    float ss = a * a + b * b + c * c + d * d;

#pragma unroll
    for (int off = 32; off > 0; off >>= 1) {
        s += __shfl_down(s, off);
        ss += __shfl_down(ss, off);
    }
    __shared__ float sbuf[4], ssbuf[4];
    const int wave = tid >> 6;
    if ((tid & 63) == 0) { sbuf[wave] = s; ssbuf[wave] = ss; }
    __syncthreads();
    const float S = sbuf[0] + sbuf[1] + sbuf[2] + sbuf[3];
    const float SS = ssbuf[0] + ssbuf[1] + ssbuf[2] + ssbuf[3];
    const float mu = S * (1.f / D_MODEL);
    const float var = SS * (1.f / D_MODEL) - mu * mu;
    const float r = rsqrtf(var + 1e-5f);

    a = (a - mu) * r; b = (b - mu) * r; c = (c - mu) * r; d = (d - mu) * r;
    u.x = (unsigned)f2bf(a) | ((unsigned)f2bf(b) << 16);
    u.y = (unsigned)f2bf(c) | ((unsigned)f2bf(d) << 16);
    *(uint2*)x = u;
}

// ---------------------------------------------------------------------------
// ONE prep dispatch (flattened 1-D grid), covering:
//  blocks [0, 6144): weight prep, 6 z-slices of 1024 blocks each
//      z=0..4: transpose+convert (wq, mlp0..2, w_out) -> bf16 N-major wt+z*DD
//      z=5:    plain convert W3 -> wt+5*DD
//  blocks [6144, 6144+M*D/2048): x fp32 -> bf16 into Q (8 elems/thread)
//  blocks [last 32): bias_compose: bf[n] = b3 @ Wout + bout, split-K in block
// ---------------------------------------------------------------------------
__global__ __launch_bounds__(256) void prep_all(
    const float* __restrict__ wq, const float* __restrict__ mlp_w,
    const float* __restrict__ w_out, const float* __restrict__ x,
    const float* __restrict__ b3, const float* __restrict__ bout,
    ushort_t* __restrict__ wt, ushort_t* __restrict__ Q,
    float* __restrict__ bf, int nxblk)
{
    const int blk = blockIdx.x;
    const int tid = threadIdx.x;

    if (blk < 6144) {                    // ---- weight prep ----
        const int z = blk >> 10;
        const int t = blk & 1023;        // 32x32 tile index
        const int k0 = (t >> 5) * 32;
        const int n0 = (t & 31) * 32;
        const int r = tid >> 5;          // 0..7
        const int c = tid & 31;          // 0..31

        if (z == 5) {                    // plain convert W3
            const float* src = mlp_w + (size_t)3 * DD;
            ushort_t* dst = wt + (size_t)5 * DD;
#pragma unroll
            for (int i = 0; i < 4; i++) {
                size_t idx = (size_t)(k0 + r + 8 * i) * D_MODEL + n0 + c;
                dst[idx] = f2bf(src[idx]);
            }
            return;
        }
        const float* src = (z == 0) ? wq : (z < 4) ? (mlp_w + (size_t)(z - 1) * DD) : w_out;
        ushort_t* dst = wt + (size_t)z * DD;
        __shared__ float tile[32][33];
#pragma unroll
        for (int i = 0; i < 4; i++)
            tile[r + 8 * i][c] = src[(size_t)(k0 + r + 8 * i) * D_MODEL + n0 + c];
        __syncthreads();
#pragma unroll
        for (int i = 0; i < 4; i++)
            dst[(size_t)(n0 + r + 8 * i) * D_MODEL + k0 + c] = f2bf(tile[c][r + 8 * i]);
        return;
    }
    if (blk < 6144 + nxblk) {            // ---- x -> bf16 ----
        int i = (blk - 6144) * 256 + tid;
        const float4* p = (const float4*)(x + (size_t)i * 8);
        float4 v0 = p[0], v1 = p[1];
        union { ushort_t u[8]; uint4 v; } pk;
        pk.u[0] = f2bf(v0.x); pk.u[1] = f2bf(v0.y);
        pk.u[2] = f2bf(v0.z); pk.u[3] = f2bf(v0.w);
        pk.u[4] = f2bf(v1.x); pk.u[5] = f2bf(v1.y);
        pk.u[6] = f2bf(v1.z); pk.u[7] = f2bf(v1.w);
        *(uint4*)(Q + (size_t)i * 8) = pk.v;
        return;
    }
    // ---- bias_compose: 32 blocks, each 32 n-cols, split-K 8-way ----
    {
        const int b = blk - 6144 - nxblk;        // 0..31
        const int n = b * 32 + (tid & 31);
        const int kg = tid >> 5;                 // 0..7
        float s = 0.f;
        for (int k = kg * 128; k < (kg + 1) * 128; k++)
            s = fmaf(b3[k], w_out[(size_t)k * D_MODEL + n], s);
        __shared__ float red[8][32];
        red[kg][tid & 31] = s;
        __syncthreads();
        if (kg == 0) {
            float t = 0.f;
#pragma unroll
            for (int j = 0; j < 8; j++) t += red[j][tid & 31];
            bf[n] = t + bout[n];
        }
    }
}

// ---------------------------------------------------------------------------
extern "C" void kernel_launch(void* const* d_in, const int* in_sizes, int n_in,
                              void* d_out, int out_size, void* d_ws, size_t ws_size,
                              hipStream_t stream)
{
    const float* x     = (const float*)d_in[0];
    const float* wq    = (const float*)d_in[1];
    const float* bq    = (const float*)d_in[2];
    const float* mlp_w = (const float*)d_in[3];
    const float* mlp_b = (const float*)d_in[4];
    const float* w_out = (const float*)d_in[5];
    const float* b_out = (const float*)d_in[6];

    const int D = D_MODEL;
    const int M = in_sizes[0] / D;   // 16384

    // ws layout (ushort units):
    // wt[0..5)=transposed weights | [5DD,6DD)=W3 plain | [6DD,7DD)=WfT
    // | Q (M*D) | bf (1024 fp32)
    ushort_t* wt  = (ushort_t*)d_ws;
    ushort_t* w3b = wt + (size_t)5 * DD;
    ushort_t* wtF = wt + (size_t)6 * DD;
    ushort_t* Q   = wt + (size_t)7 * DD;
    float*    bf  = (float*)(Q + (size_t)M * D);
    ushort_t* P   = (ushort_t*)d_out;   // bf16 acts alias d_out's fp32 buffer

    // 1. all prep in one dispatch
    const int nxblk = M * D / 2048;     // x-convert blocks (8 elems/thread)
    prep_all<<<6144 + nxblk + 32, 256, 0, stream>>>(
        wq, mlp_w, w_out, x, mlp_b + 3 * D, b_out, wt, Q, bf, nxblk);
    // 2. Wf^T = Wout^T @ W3^T  (N-major rep of Wf = W3*Wout)
    gemm_bf16<ACT_NONE, 0, 0><<<dim3(8, 8), 256, 0, stream>>>(
        wt + (size_t)4 * DD, w3b, nullptr, wtF, 1024);

    dim3 grid(M / 128, D / 128);
    // 3. q = x @ wq + bq -> P
    gemm_bf16<ACT_NONE, 0, 1><<<grid, 256, 0, stream>>>(Q, wt + (size_t)0 * DD, bq, P, M);
    // 4. LN in place on P
    layernorm_bf16<<<M, 256, 0, stream>>>(P);
    // 5-7. MLP layers 0..2 with SiLU
    gemm_bf16<ACT_SILU, 0, 1><<<grid, 256, 0, stream>>>(P, wt + (size_t)1 * DD, mlp_b + 0 * D, Q, M);
    gemm_bf16<ACT_SILU, 0, 1><<<grid, 256, 0, stream>>>(Q, wt + (size_t)2 * DD, mlp_b + 1 * D, P, M);
    gemm_bf16<ACT_SILU, 0, 1><<<grid, 256, 0, stream>>>(P, wt + (size_t)3 * DD, mlp_b + 2 * D, Q, M);
    // 8. fused (layer3 + out proj): out = h3 @ Wf + bf -> d_out fp32
    //    (reads Q in ws, so no alias hazard with d_out)
    gemm_bf16<ACT_NONE, 1, 1><<<grid, 256, 0, stream>>>(Q, wtF, bf, d_out, M);
}